// Round 10
// baseline (1523.313 us; speedup 1.0000x reference)
//
#include <hip/hip_runtime.h>
#include <hip/hip_bf16.h>

#define EXPERTS 8
#define TOK 2048
#define DM 1024
#define DH 4096

#define BM 128
#define BN 128
#define BK 32
#define LSTR 40

typedef __bf16 bf16x8 __attribute__((ext_vector_type(8)));
typedef float  f32x4  __attribute__((ext_vector_type(4)));

static __device__ __forceinline__ bf16x8 cvt8(float4 a, float4 b) {
    bf16x8 r;
    r[0] = (__bf16)a.x; r[1] = (__bf16)a.y; r[2] = (__bf16)a.z; r[3] = (__bf16)a.w;
    r[4] = (__bf16)b.x; r[5] = (__bf16)b.y; r[6] = (__bf16)b.z; r[7] = (__bf16)b.w;
    return r;
}

static __device__ __forceinline__ void gload16(const __bf16* g, __bf16* l) {
    __builtin_amdgcn_global_load_lds(
        (__attribute__((address_space(1))) void*)g,
        (__attribute__((address_space(3))) void*)l, 16, 0, 0);
}

#define BARRIER() asm volatile("s_barrier" ::: "memory")
#define SB()      __builtin_amdgcn_sched_barrier(0)
#define LGKM0()   do { asm volatile("s_waitcnt lgkmcnt(0)" ::: "memory"); SB(); } while (0)
#define LGKM1()   do { asm volatile("s_waitcnt lgkmcnt(1)" ::: "memory"); SB(); } while (0)
#define LGKM2()   do { asm volatile("s_waitcnt lgkmcnt(2)" ::: "memory"); SB(); } while (0)
#define LGKM4()   do { asm volatile("s_waitcnt lgkmcnt(4)" ::: "memory"); SB(); } while (0)
#define LGKM5()   do { asm volatile("s_waitcnt lgkmcnt(5)" ::: "memory"); SB(); } while (0)
#define LGKM6()   do { asm volatile("s_waitcnt lgkmcnt(6)" ::: "memory"); SB(); } while (0)
#define VMW0()    asm volatile("s_waitcnt vmcnt(0)" ::: "memory")

// single fused fp32->bf16 convert for x, w1, w2 (one launch)
__global__ __launch_bounds__(256)
void cvt_all(const float* __restrict__ x,  const float* __restrict__ w1,
             const float* __restrict__ w2, __bf16* __restrict__ xb,
             __bf16* __restrict__ w1b,     __bf16* __restrict__ w2b,
             int nx, int nw1, int ntot) {
    int i = blockIdx.x * blockDim.x + threadIdx.x;
    const int stride = gridDim.x * blockDim.x;
    for (; i < ntot; i += stride) {
        const float* src; __bf16* dst; int off;
        if (i < nx)            { src = x;  dst = xb;  off = i; }
        else if (i < nx + nw1) { src = w1; dst = w1b; off = i - nx; }
        else                   { src = w2; dst = w2b; off = i - nx - nw1; }
        const float4* p = (const float4*)src + (size_t)off * 2;
        float4 a = p[0], b = p[1];
        *((bf16x8*)dst + off) = cvt8(a, b);
    }
}

// ---- 256x(NF*128) bf16 GEMM (C = A * B^T), SINGLE-buffer, 2 blocks/CU ----
// 8 waves (2M x 4N), per-wave 128 x (NF*32) out, BK=64.
// LDS = A 32KB + B NF*16KB (64KB @ NF=2, 48KB @ NF=1) -> 2 blocks/CU.
// Per K-tile t, 4 phases; tile t+1 staged into the SAME buffer:
//  P0: VMW0 (own stages drained); BAR (all landed); read al+bl; counted lgkm; MFMA al*bl
//  P1: read bh; BAR; counted lgkm; MFMA al*bh
//  P2: read ah; BAR [all waves' P1 lgkm0 done -> B retired]; stage B(t+1); lgkm4; MFMA ah*bh
//  P3: BAR [P2 lgkm0 done -> A retired]; stage A(t+1); MFMA ah*bl
// Proof sketch: every read-phase ends LGKM0, so passing BAR#p implies all
// reads <= p-1 complete block-wide; stages target regions last read <= p-1.
// Read-after-stage: per-wave VMW0 precedes BAR#P0.
template<int NF, bool RELU, bool OUT_BF16>
__global__ __launch_bounds__(512, 4)
void gemm8s(const __bf16* __restrict__ Ap, const __bf16* __restrict__ Bp,
            void* __restrict__ Cp, int N, int K, int tiles_m, int tiles_n,
            size_t sA, size_t sB, size_t sC)
{
    __shared__ __bf16 lds[16384 + NF * 8192];   // A: [0,16384) B: [16384,...)

    int bid = blockIdx.x;                 // grid % 8 == 0 for all launches
    const int chunk = gridDim.x >> 3;
    bid = (bid & 7) * chunk + (bid >> 3);

    const int per_e = tiles_m * tiles_n;
    const int e  = bid / per_e;
    const int tt = bid - e * per_e;
    const int tn = tt / tiles_m;          // consecutive blocks share B panel
    const int tm = tt - tn * tiles_m;

    const int tid = threadIdx.x;
    const int l   = tid & 63;
    const int wid = tid >> 6;             // 0..7
    const int wr  = wid >> 2;             // 0..1
    const int wc  = wid & 3;              // 0..3
    const int lr  = l & 15;
    const int kg  = l >> 4;               // 0..3
    const int lq  = l >> 3;               // 0..7
    const int swz_e = ((l & 7) ^ lq) << 3;        // staging src swizzle (elems)

    const int cc0  = (kg * 16) ^ ((l & 7) << 4);  // ds_read col byte, kstep 0
    const int cc1  = cc0 ^ 64;                    // kstep 1
    const int rowA = (wr * 128 + lr) * 128;
    const int rowB = (wc * (NF * 32) + lr) * 128;

    const __bf16* Ag = Ap + e * sA + (size_t)(tm * 256) * K;
    const __bf16* Bg = Bp + e * sB + (size_t)(tn * (NF * 128)) * K;

    // stage one 64-row unit of matrix at lds element offset matoff
    auto stage_u = [&](const __bf16* g, int matoff, int u, int kt2) {
        const __bf16* s0 = g + (size_t)(u * 64 + wid * 8 + lq) * K + kt2 * 64 + swz_e;
        gload16(s0, &lds[matoff + u * 4096 + wid * 512]);
    };

    f32x4 acc[8][2 * NF];
    #pragma unroll
    for (int m = 0; m < 8; ++m)
        #pragma unroll
        for (int n = 0; n < 2 * NF; ++n)
            acc[m][n] = (f32x4){0.f, 0.f, 0.f, 0.f};

    const char* Ab = (const char*)&lds[0] + rowA;
    const char* Bb = (const char*)&lds[16384] + rowB;

    bf16x8 al[4][2], ah[4][2], bl[NF][2], bh[NF][2];

    auto rdA_k = [&](bf16x8 (&dst)[4][2], int half, int kk) {
        const int cc = kk ? cc1 : cc0;
        #pragma unroll
        for (int mf = 0; mf < 4; ++mf)
            dst[mf][kk] = *(const bf16x8*)(Ab + (half * 4 + mf) * 2048 + cc);
    };
    auto rdB_k = [&](bf16x8 (&dst)[NF][2], int half, int kk) {
        const int cc = kk ? cc1 : cc0;
        #pragma unroll
        for (int nf = 0; nf < NF; ++nf)
            dst[nf][kk] = *(const bf16x8*)(Bb + (half * NF + nf) * 2048 + cc);
    };
    auto mma = [&](bf16x8 (&af)[4][2], bf16x8 (&bf_)[NF][2], int mo, int no, int kk) {
        #pragma unroll
        for (int mf = 0; mf < 4; ++mf)
            #pragma unroll
            for (int nf = 0; nf < NF; ++nf)
                acc[mo + mf][no + nf] = __builtin_amdgcn_mfma_f32_16x16x32_bf16(
                    af[mf][kk], bf_[nf][kk], acc[mo + mf][no + nf], 0, 0, 0);
    };

    const int NT = K / 64;

    // Prologue: stage tile 0 (A units 0-3, B units 0..2NF-1)
    #pragma unroll
    for (int u = 0; u < 4; ++u) stage_u(Ag, 0, u, 0);
    #pragma unroll
    for (int u = 0; u < 2 * NF; ++u) stage_u(Bg, 16384, u, 0);

    for (int t = 0; t < NT; ++t) {
        const bool pf = (t + 1 < NT);

        // ---- P0: own stages drained, then block-wide visible
        VMW0();
        BARRIER();
        rdA_k(al, 0, 0); rdB_k(bl, 0, 0);
        SB();
        rdA_k(al, 0, 1); rdB_k(bl, 0, 1);
        if constexpr (NF == 2) LGKM6(); else LGKM5();
        mma(al, bl, 0, 0, 0);
        LGKM0();
        mma(al, bl, 0, 0, 1);

        // ---- P1
        rdB_k(bh, 1, 0);
        SB();
        rdB_k(bh, 1, 1);
        BARRIER();
        if constexpr (NF == 2) LGKM2(); else LGKM1();
        mma(al, bh, 0, NF, 0);
        LGKM0();
        mma(al, bh, 0, NF, 1);

        // ---- P2: B region retired after this barrier -> stage B(t+1)
        rdA_k(ah, 1, 0);
        SB();
        rdA_k(ah, 1, 1);
        BARRIER();
        if (pf) {
            #pragma unroll
            for (int u = 0; u < 2 * NF; ++u) stage_u(Bg, 16384, u, t + 1);
        }
        LGKM4();
        mma(ah, bh, 4, NF, 0);
        LGKM0();
        mma(ah, bh, 4, NF, 1);

        // ---- P3: A region retired after this barrier -> stage A(t+1)
        BARRIER();
        if (pf) {
            #pragma unroll
            for (int u = 0; u < 4; ++u) stage_u(Ag, 0, u, t + 1);
        }
        mma(ah, bl, 4, 0, 0);
        mma(ah, bl, 4, 0, 1);
    }

    // Epilogue. C/D: col = lane&15, row = (lane>>4)*4 + reg.
    const int orow = tm * 256 + wr * 128 + kg * 4;
    const int ocol = tn * (NF * 128) + wc * (NF * 32) + lr;
    if constexpr (OUT_BF16) {
        __bf16* C = (__bf16*)Cp + e * sC;
        #pragma unroll
        for (int mf = 0; mf < 8; ++mf)
            #pragma unroll
            for (int j = 0; j < 4; ++j) {
                const size_t base = (size_t)(orow + mf * 16 + j) * N + ocol;
                #pragma unroll
                for (int nf = 0; nf < 2 * NF; ++nf) {
                    float v = acc[mf][nf][j];
                    if (RELU) v = fmaxf(v, 0.f);
                    C[base + nf * 16] = (__bf16)v;
                }
            }
    } else {
        float* C = (float*)Cp + e * sC;
        #pragma unroll
        for (int mf = 0; mf < 8; ++mf)
            #pragma unroll
            for (int j = 0; j < 4; ++j) {
                const size_t base = (size_t)(orow + mf * 16 + j) * N + ocol;
                #pragma unroll
                for (int nf = 0; nf < 2 * NF; ++nf) {
                    float v = acc[mf][nf][j];
                    if (RELU) v = fmaxf(v, 0.f);
                    C[base + nf * 16] = v;
                }
            }
    }
}

// ---------------- fallback 128x128 kernel (tiers B-E) ----------------
template<int AMODE, int BMODE, bool RELU, bool OUT_BF16>
__global__ __launch_bounds__(256)
void gemm2(const void* __restrict__ Ap, const void* __restrict__ Bp,
           void* __restrict__ Cp, int N, int K, int tiles_m, int tiles_n,
           size_t sA, size_t sB, size_t sC)
{
    constexpr int LA = (AMODE == 0) ? BK : LSTR;
    constexpr int LB = (BMODE == 0) ? BK : LSTR;
    __shared__ __bf16 As[BM * LA];
    __shared__ __bf16 Bs[BN * LB];

    int bid = blockIdx.x;
    const int chunk = gridDim.x >> 3;
    bid = (bid & 7) * chunk + (bid >> 3);

    const int per_e = tiles_m * tiles_n;
    const int e  = bid / per_e;
    const int t  = bid - e * per_e;
    const int tn = t / tiles_m;
    const int tm = t - tn * tiles_m;

    const int tid = threadIdx.x;
    const int l   = tid & 63;
    const int wid = tid >> 6;
    const int wr  = wid >> 1, wc = wid & 1;
    const int lr  = l & 15;
    const int kg  = l >> 4;
    const int srow = tid >> 1;
    const int scol = (tid & 1) << 4;

    const __bf16* gA = nullptr; __bf16* lA = nullptr;
    const float*  pAf = nullptr; __bf16* aWr = nullptr;
    float4 A0, A1, A2, A3;
    if constexpr (AMODE == 0) {
        gA = (const __bf16*)Ap + e * sA
           + (size_t)(tm * BM + wid * 16 + (l >> 2)) * K + (l & 3) * 8;
        lA = As + wid * 512;
    } else {
        pAf = (const float*)Ap + e * sA + (size_t)(tm * BM + srow) * K + scol;
        aWr = As + srow * LA + scol;
        A0 = *(const float4*)(pAf);      A1 = *(const float4*)(pAf + 4);
        A2 = *(const float4*)(pAf + 8);  A3 = *(const float4*)(pAf + 12);
    }
    const __bf16* gB = nullptr; __bf16* lB = nullptr;
    const float*  pBf = nullptr; __bf16* bWr = nullptr;
    float4 B0, B1, B2, B3;
    if constexpr (BMODE == 0) {
        gB = (const __bf16*)Bp + e * sB
           + (size_t)(tn * BN + wid * 16 + (l >> 2)) * K + (l & 3) * 8;
        lB = Bs + wid * 512;
    } else {
        pBf = (const float*)Bp + e * sB + (size_t)(tn * BN + srow) * K + scol;
        bWr = Bs + srow * LB + scol;
        B0 = *(const float4*)(pBf);      B1 = *(const float4*)(pBf + 4);
        B2 = *(const float4*)(pBf + 8);  B3 = *(const float4*)(pBf + 12);
    }

    const __bf16* aRd = As + (wr * 64 + lr) * LA + kg * 8;
    const __bf16* bRd = Bs + (wc * 64 + lr) * LB + kg * 8;

    f32x4 acc[4][4];
    #pragma unroll
    for (int m = 0; m < 4; ++m)
        #pragma unroll
        for (int n = 0; n < 4; ++n)
            acc[m][n] = (f32x4){0.f, 0.f, 0.f, 0.f};

    const int NT = K / BK;
    for (int kt = 0; kt < NT; ++kt) {
        if (kt) __syncthreads();
        if constexpr (AMODE == 0) {
            gload16(gA, lA);
            gload16(gA + (size_t)64 * K, lA + 2048);
            gA += BK;
        } else {
            *(bf16x8*)(aWr)     = cvt8(A0, A1);
            *(bf16x8*)(aWr + 8) = cvt8(A2, A3);
        }
        if constexpr (BMODE == 0) {
            gload16(gB, lB);
            gload16(gB + (size_t)64 * K, lB + 2048);
            gB += BK;
        } else {
            *(bf16x8*)(bWr)     = cvt8(B0, B1);
            *(bf16x8*)(bWr + 8) = cvt8(B2, B3);
        }
        __syncthreads();

        if (kt + 1 < NT) {
            if constexpr (AMODE == 2) {
                pAf += BK;
                A0 = *(const float4*)(pAf);      A1 = *(const float4*)(pAf + 4);
                A2 = *(const float4*)(pAf + 8);  A3 = *(const float4*)(pAf + 12);
            }
            if constexpr (BMODE == 2) {
                pBf += BK;
                B0 = *(const float4*)(pBf);      B1 = *(const float4*)(pBf + 4);
                B2 = *(const float4*)(pBf + 8);  B3 = *(const float4*)(pBf + 12);
            }
        }

        bf16x8 af[4], bfr[4];
        #pragma unroll
        for (int m = 0; m < 4; ++m) af[m]  = *(const bf16x8*)(aRd + m * 16 * LA);
        #pragma unroll
        for (int n = 0; n < 4; ++n) bfr[n] = *(const bf16x8*)(bRd + n * 16 * LB);
        #pragma unroll
        for (int m = 0; m < 4; ++m)
            #pragma unroll
            for (int n = 0; n < 4; ++n)
                acc[m][n] = __builtin_amdgcn_mfma_f32_16x16x32_bf16(af[m], bfr[n], acc[m][n], 0, 0, 0);
    }

    const int orow = tm * BM + wr * 64 + kg * 4;
    const int ocol = tn * BN + wc * 64 + lr;
    if constexpr (OUT_BF16) {
        __bf16* C = (__bf16*)Cp + e * sC;
        #pragma unroll
        for (int m = 0; m < 4; ++m)
            #pragma unroll
            for (int j = 0; j < 4; ++j) {
                const size_t base = (size_t)(orow + m * 16 + j) * N + ocol;
                #pragma unroll
                for (int n = 0; n < 4; ++n) {
                    float v = acc[m][n][j];
                    if (RELU) v = fmaxf(v, 0.f);
                    C[base + n * 16] = (__bf16)v;
                }
            }
    } else {
        float* C = (float*)Cp + e * sC;
        #pragma unroll
        for (int m = 0; m < 4; ++m)
            #pragma unroll
            for (int j = 0; j < 4; ++j) {
                const size_t base = (size_t)(orow + m * 16 + j) * N + ocol;
                #pragma unroll
                for (int n = 0; n < 4; ++n) {
                    float v = acc[m][n][j];
                    if (RELU) v = fmaxf(v, 0.f);
                    C[base + n * 16] = v;
                }
            }
    }
}

extern "C" void kernel_launch(void* const* d_in, const int* in_sizes, int n_in,
                              void* d_out, int out_size, void* d_ws, size_t ws_size,
                              hipStream_t stream) {
    const float* x  = (const float*)d_in[0];   // [8, 2048, 1024]
    const float* w1 = (const float*)d_in[1];   // [8, 4096, 1024]
    const float* w2 = (const float*)d_in[2];   // [8, 1024, 4096]
    float* out = (float*)d_out;                // [8, 2048, 1024]

    const size_t SZ_F  = (size_t)EXPERTS * TOK * DH * sizeof(__bf16);  // 134.2 MB
    const size_t SZ_X  = (size_t)EXPERTS * TOK * DM * sizeof(__bf16);
    const size_t SZ_W1 = (size_t)EXPERTS * DH * DM * sizeof(__bf16);
    const size_t SZ_W2 = (size_t)EXPERTS * DM * DH * sizeof(__bf16);

    char* wsb = (char*)d_ws;
    __bf16* ffn1 = (__bf16*)wsb;

    const dim3 blk(256);
    const dim3 cgrid(2048);
    const int NX  = EXPERTS * TOK * DM / 8;
    const int NW1 = EXPERTS * DH * DM / 8;
    const int NW2 = EXPERTS * DM * DH / 8;

    const size_t eA1 = (size_t)TOK * DM, eB1 = (size_t)DH * DM, eC1 = (size_t)TOK * DH;
    const size_t eA2 = (size_t)TOK * DH, eB2 = (size_t)DM * DH, eC2 = (size_t)TOK * DM;

    if (ws_size >= SZ_F + SZ_X + SZ_W1 + SZ_W2) {
        // Tier A: fused cvt; GEMM1 256x256, GEMM2 256x128 — both 2 blocks/CU
        __bf16* xb  = (__bf16*)(wsb + SZ_F);
        __bf16* w1b = (__bf16*)(wsb + SZ_F + SZ_X);
        __bf16* w2b = (__bf16*)(wsb + SZ_F + SZ_X + SZ_W1);
        hipLaunchKernelGGL(cvt_all, cgrid, blk, 0, stream,
            x, w1, w2, xb, w1b, w2b, NX, NW1, NX + NW1 + NW2);
        const dim3 g1(EXPERTS * (TOK / 256) * (DH / 256));   // 1024
        const dim3 g2(EXPERTS * (TOK / 256) * (DM / 128));   // 512
        hipLaunchKernelGGL((gemm8s<2, true, true>), g1, dim3(512), 0, stream,
            xb, w1b, ffn1, DH, DM, TOK / 256, DH / 256, eA1, eB1, eC1);
        hipLaunchKernelGGL((gemm8s<1, false, false>), g2, dim3(512), 0, stream,
            ffn1, w2b, out, DM, DH, TOK / 256, DM / 128, eA2, eB2, eC2);
    } else if (ws_size >= SZ_F + SZ_X + SZ_W1) {
        __bf16* xb  = (__bf16*)(wsb + SZ_F);
        __bf16* w1b = (__bf16*)(wsb + SZ_F + SZ_X);
        hipLaunchKernelGGL(cvt_all, cgrid, blk, 0, stream,
            x, w1, w1, xb, w1b, w1b, NX, NW1, NX + NW1);
        const dim3 g1(EXPERTS * (TOK / 256) * (DH / 256));
        const dim3 g2(EXPERTS * (TOK / BM) * (DM / BN));
        hipLaunchKernelGGL((gemm8s<2, true, true>), g1, dim3(512), 0, stream,
            xb, w1b, ffn1, DH, DM, TOK / 256, DH / 256, eA1, eB1, eC1);
        hipLaunchKernelGGL((gemm2<0, 2, false, false>), g2, blk, 0, stream,
            ffn1, w2, out, DM, DH, TOK / BM, DM / BN, eA2, eB2, eC2);
    } else if (ws_size >= SZ_F + SZ_W1) {
        __bf16* w1b = (__bf16*)(wsb + SZ_F);
        hipLaunchKernelGGL(cvt_all, cgrid, blk, 0, stream,
            w1, w1, w1, w1b, w1b, w1b, NW1, 0, NW1);
        const dim3 g1(EXPERTS * (TOK / BM) * (DH / BN));
        const dim3 g2(EXPERTS * (TOK / BM) * (DM / BN));
        hipLaunchKernelGGL((gemm2<2, 0, true, true>), g1, blk, 0, stream,
            x, w1b, ffn1, DH, DM, TOK / BM, DH / BN, eA1, eB1, eC1);
        hipLaunchKernelGGL((gemm2<0, 2, false, false>), g2, blk, 0, stream,
            ffn1, w2, out, DM, DH, TOK / BM, DM / BN, eA2, eB2, eC2);
    } else if (ws_size >= SZ_F) {
        const dim3 g1(EXPERTS * (TOK / BM) * (DH / BN));
        const dim3 g2(EXPERTS * (TOK / BM) * (DM / BN));
        hipLaunchKernelGGL((gemm2<2, 2, true, true>), g1, blk, 0, stream,
            x, w1, ffn1, DH, DM, TOK / BM, DH / BN, eA1, eB1, eC1);
        hipLaunchKernelGGL((gemm2<0, 2, false, false>), g2, blk, 0, stream,
            ffn1, w2, out, DM, DH, TOK / BM, DM / BN, eA2, eB2, eC2);
    } else {
        int rows = (int)((ws_size / ((size_t)DH * sizeof(__bf16))) / BM) * BM;
        if (rows <= 0) rows = BM;
        if (rows > TOK) rows = TOK;
        for (int e = 0; e < EXPERTS; ++e) {
            for (int r0 = 0; r0 < TOK; r0 += rows) {
                int mr = (TOK - r0 < rows) ? (TOK - r0) : rows;
                dim3 cg1((mr / BM) * (DH / BN));
                hipLaunchKernelGGL((gemm2<2, 2, true, true>), cg1, blk, 0, stream,
                    x + ((size_t)e * TOK + r0) * DM, w1 + (size_t)e * DH * DM, ffn1,
                    DH, DM, mr / BM, DH / BN, (size_t)0, (size_t)0, (size_t)0);
                dim3 cg2((mr / BM) * (DM / BN));
                hipLaunchKernelGGL((gemm2<0, 2, false, false>), cg2, blk, 0, stream,
                    ffn1, w2 + (size_t)e * DM * DH, out + ((size_t)e * TOK + r0) * DM,
                    DM, DH, mr / BM, DM / BN, (size_t)0, (size_t)0, (size_t)0);
            }
        }
    }
}

// Round 11
// 332.518 us; speedup vs baseline: 4.5811x; 4.5811x over previous
//
#include <hip/hip_runtime.h>
#include <hip/hip_bf16.h>

#define EXPERTS 8
#define TOK 2048
#define DM 1024
#define DH 4096

#define BM 128
#define BN 128
#define BK 32
#define LSTR 40

typedef __bf16 bf16x8 __attribute__((ext_vector_type(8)));
typedef float  f32x4  __attribute__((ext_vector_type(4)));

static __device__ __forceinline__ bf16x8 cvt8(float4 a, float4 b) {
    bf16x8 r;
    r[0] = (__bf16)a.x; r[1] = (__bf16)a.y; r[2] = (__bf16)a.z; r[3] = (__bf16)a.w;
    r[4] = (__bf16)b.x; r[5] = (__bf16)b.y; r[6] = (__bf16)b.z; r[7] = (__bf16)b.w;
    return r;
}

static __device__ __forceinline__ void gload16(const __bf16* g, __bf16* l) {
    __builtin_amdgcn_global_load_lds(
        (__attribute__((address_space(1))) void*)g,
        (__attribute__((address_space(3))) void*)l, 16, 0, 0);
}

#define BARRIER() asm volatile("s_barrier" ::: "memory")
#define SB()      __builtin_amdgcn_sched_barrier(0)
#define LGKM0()   do { asm volatile("s_waitcnt lgkmcnt(0)" ::: "memory"); SB(); } while (0)
#define LGKM2()   do { asm volatile("s_waitcnt lgkmcnt(2)" ::: "memory"); SB(); } while (0)
#define LGKM4()   do { asm volatile("s_waitcnt lgkmcnt(4)" ::: "memory"); SB(); } while (0)
#define LGKM6()   do { asm volatile("s_waitcnt lgkmcnt(6)" ::: "memory"); SB(); } while (0)
#define VMW4()    asm volatile("s_waitcnt vmcnt(4)" ::: "memory")
#define VMW0()    asm volatile("s_waitcnt vmcnt(0)" ::: "memory")

// single fused fp32->bf16 convert for x, w1, w2 (one launch)
__global__ __launch_bounds__(256)
void cvt_all(const float* __restrict__ x,  const float* __restrict__ w1,
             const float* __restrict__ w2, __bf16* __restrict__ xb,
             __bf16* __restrict__ w1b,     __bf16* __restrict__ w2b,
             int nx, int nw1, int ntot) {
    int i = blockIdx.x * blockDim.x + threadIdx.x;
    const int stride = gridDim.x * blockDim.x;
    for (; i < ntot; i += stride) {
        const float* src; __bf16* dst; int off;
        if (i < nx)            { src = x;  dst = xb;  off = i; }
        else if (i < nx + nw1) { src = w1; dst = w1b; off = i - nx; }
        else                   { src = w2; dst = w2b; off = i - nx - nw1; }
        const float4* p = (const float4*)src + (size_t)off * 2;
        float4 a = p[0], b = p[1];
        *((bf16x8*)dst + off) = cvt8(a, b);
    }
}

// -------- 256x256 8-phase bf16 GEMM (C = A * B^T), SINGLE barrier/phase ----
// (Round-9 kernel, verbatim. Round-10's __launch_bounds__(512,4) forced a
// 64-VGPR cap -> full scratch spill -> 4.6x regression; reverted.)
// 8 waves (2Mx4N), per-wave 128x64 out, BK=64, 2 K-tiles per outer iter,
// buf0 even tiles / buf1 odd. ONE s_barrier per phase; stages issued AFTER
// the barrier. Safety invariant: every read-phase ends in lgkmcnt(0), so
// "wave passed bar(p)" => "all its reads <= p-1 complete"; each phase-p
// stage targets a region last read in phase <= p-1 (verified per phase).
// vmcnt(4) at P0/P4 tops waits loads issued >= 4 phases earlier.
template<bool RELU, bool OUT_BF16>
__global__ __launch_bounds__(512, 2)
void gemm8(const __bf16* __restrict__ Ap, const __bf16* __restrict__ Bp,
           void* __restrict__ Cp, int N, int K, int tiles_m, int tiles_n,
           size_t sA, size_t sB, size_t sC)
{
    __shared__ __bf16 lds[2][2][16384];   // [buf][A/B][256*64] = 128 KiB

    int bid = blockIdx.x;                 // grid % 8 == 0 for all launches
    const int chunk = gridDim.x >> 3;
    bid = (bid & 7) * chunk + (bid >> 3);

    const int per_e = tiles_m * tiles_n;
    const int e  = bid / per_e;
    const int tt = bid - e * per_e;
    const int tn = tt / tiles_m;          // consecutive blocks share B panel
    const int tm = tt - tn * tiles_m;

    const int tid = threadIdx.x;
    const int l   = tid & 63;
    const int wid = tid >> 6;             // 0..7
    const int wr  = wid >> 2;             // 0..1
    const int wc  = wid & 3;              // 0..3
    const int lr  = l & 15;
    const int kg  = l >> 4;               // 0..3
    const int lq  = l >> 3;               // 0..7
    const int swz_e = ((l & 7) ^ lq) << 3;        // staging src swizzle (elems)

    const int cc0  = (kg * 16) ^ ((l & 7) << 4);  // ds_read col byte, kstep 0
    const int cc1  = cc0 ^ 64;                    // kstep 1
    const int rowA = (wr * 128 + lr) * 128;
    const int rowB = (wc * 64  + lr) * 128;

    const __bf16* Ag = Ap + e * sA + (size_t)(tm * 256) * K;
    const __bf16* Bg = Bp + e * sB + (size_t)(tn * 256) * K;

    // stage half h (128 rows x 64 cols) of matrix mat, K-tile kt2, buffer c2
    auto stage_half = [&](const __bf16* g, int mat, int c2, int h, int kt2) {
        const __bf16* s0 = g + (size_t)(h * 128 + wid * 8 + lq) * K + kt2 * 64 + swz_e;
        gload16(s0,                  &lds[c2][mat][h * 8192 + wid * 512]);
        gload16(s0 + (size_t)64 * K, &lds[c2][mat][h * 8192 + 4096 + wid * 512]);
    };

    f32x4 acc[8][4];
    #pragma unroll
    for (int m = 0; m < 8; ++m)
        #pragma unroll
        for (int n = 0; n < 4; ++n)
            acc[m][n] = (f32x4){0.f, 0.f, 0.f, 0.f};

    const char* A0b = (const char*)&lds[0][0][0] + rowA;
    const char* B0b = (const char*)&lds[0][1][0] + rowB;
    const char* A1b = (const char*)&lds[1][0][0] + rowA;
    const char* B1b = (const char*)&lds[1][1][0] + rowB;

    bf16x8 al[4][2], ah[4][2], bl[2][2], bh[2][2];

    // one K-half of a fragment set (static kk index -> no scratch)
    auto rdA_k = [&](bf16x8 (&dst)[4][2], const char* base, int half, int kk) {
        const int cc = kk ? cc1 : cc0;
        #pragma unroll
        for (int mf = 0; mf < 4; ++mf)
            dst[mf][kk] = *(const bf16x8*)(base + (half * 4 + mf) * 2048 + cc);
    };
    auto rdB_k = [&](bf16x8 (&dst)[2][2], const char* base, int half, int kk) {
        const int cc = kk ? cc1 : cc0;
        #pragma unroll
        for (int nf = 0; nf < 2; ++nf)
            dst[nf][kk] = *(const bf16x8*)(base + (half * 2 + nf) * 2048 + cc);
    };
    auto mma8 = [&](bf16x8 (&af)[4][2], bf16x8 (&bf_)[2][2], int mo, int no, int kk) {
        #pragma unroll
        for (int mf = 0; mf < 4; ++mf)
            #pragma unroll
            for (int nf = 0; nf < 2; ++nf)
                acc[mo + mf][no + nf] = __builtin_amdgcn_mfma_f32_16x16x32_bf16(
                    af[mf][kk], bf_[nf][kk], acc[mo + mf][no + nf], 0, 0, 0);
    };

    const int NT = K / 64;                // even for all our launches
    const int NI = NT / 2;

    // Prologue: issue tile 0 fully + tile 1's B halves (12 loads), no wait —
    // P0's VMW4 (keeps newest 4 = B-T1) + barrier provides it.
    stage_half(Ag, 0, 0, 0, 0); stage_half(Ag, 0, 0, 1, 0);
    stage_half(Bg, 1, 0, 0, 0); stage_half(Bg, 1, 0, 1, 0);
    stage_half(Bg, 1, 1, 0, 1); stage_half(Bg, 1, 1, 1, 1);

    for (int it = 0; it < NI; ++it) {
        const int To = 2 * it + 1;        // odd tile this iter
        const int Te = 2 * it + 2;        // next even tile
        const int Tn = 2 * it + 3;        // next odd tile
        const bool pf = (it + 1 < NI);

        // ---- P0 (boundary): tile 2it (buf0) ready after VMW4+bar
        VMW4();                           // everything except newest 4 landed
        BARRIER();
        rdA_k(al, A0b, 0, 0); rdB_k(bl, B0b, 0, 0);
        SB();
        rdA_k(al, A0b, 0, 1); rdB_k(bl, B0b, 0, 1);
        stage_half(Ag, 0, 1, 0, To);      // A-h0 -> buf1 (last read prev iter)
        LGKM6();
        mma8(al, bl, 0, 0, 0);
        LGKM0();
        mma8(al, bl, 0, 0, 1);

        // ---- P1
        rdB_k(bh, B0b, 1, 0);
        SB();
        rdB_k(bh, B0b, 1, 1);
        BARRIER();
        stage_half(Ag, 0, 1, 1, To);      // A-h1 -> buf1 (last read <= prev iter)
        LGKM2();
        mma8(al, bh, 0, 2, 0);
        LGKM0();
        mma8(al, bh, 0, 2, 1);

        // ---- P2
        rdA_k(ah, A0b, 1, 0);
        SB();
        rdA_k(ah, A0b, 1, 1);
        BARRIER();
        if (pf) stage_half(Bg, 1, 0, 0, Te);  // B-h0 buf0: last read P1
        LGKM4();
        mma8(ah, bh, 4, 2, 0);
        LGKM0();
        mma8(ah, bh, 4, 2, 1);

        // ---- P3 (no reads)
        BARRIER();
        if (pf) stage_half(Bg, 1, 0, 1, Te);  // B-h1 buf0: last read P1
        mma8(ah, bl, 4, 0, 0);
        mma8(ah, bl, 4, 0, 1);

        // ---- P4 (boundary): tile To (buf1) ready after wait+bar
        if (pf) VMW4(); else VMW0();      // A-To (+B-Tn-minus) landed
        BARRIER();
        rdA_k(al, A1b, 0, 0); rdB_k(bl, B1b, 0, 0);
        SB();
        rdA_k(al, A1b, 0, 1); rdB_k(bl, B1b, 0, 1);
        if (pf) stage_half(Ag, 0, 0, 0, Te);  // A-h0 buf0: last read P2
        LGKM6();
        mma8(al, bl, 0, 0, 0);
        LGKM0();
        mma8(al, bl, 0, 0, 1);

        // ---- P5
        rdB_k(bh, B1b, 1, 0);
        SB();
        rdB_k(bh, B1b, 1, 1);
        BARRIER();
        if (pf) stage_half(Ag, 0, 0, 1, Te);  // A-h1 buf0: last read P2
        LGKM2();
        mma8(al, bh, 0, 2, 0);
        LGKM0();
        mma8(al, bh, 0, 2, 1);

        // ---- P6
        rdA_k(ah, A1b, 1, 0);
        SB();
        rdA_k(ah, A1b, 1, 1);
        BARRIER();
        if (pf) stage_half(Bg, 1, 1, 0, Tn);  // B-h0 buf1: last read P5
        LGKM4();
        mma8(ah, bh, 4, 2, 0);
        LGKM0();
        mma8(ah, bh, 4, 2, 1);

        // ---- P7 (no reads)
        BARRIER();
        if (pf) stage_half(Bg, 1, 1, 1, Tn);  // B-h1 buf1: last read P5
        mma8(ah, bl, 4, 0, 0);
        mma8(ah, bl, 4, 0, 1);
    }

    // Epilogue. C/D: col = lane&15, row = (lane>>4)*4 + reg.
    const int orow = tm * 256 + wr * 128 + kg * 4;
    const int ocol = tn * 256 + wc * 64 + lr;
    if constexpr (OUT_BF16) {
        __bf16* C = (__bf16*)Cp + e * sC;
        #pragma unroll
        for (int mf = 0; mf < 8; ++mf)
            #pragma unroll
            for (int j = 0; j < 4; ++j) {
                const size_t base = (size_t)(orow + mf * 16 + j) * N + ocol;
                #pragma unroll
                for (int nf = 0; nf < 4; ++nf) {
                    float v = acc[mf][nf][j];
                    if (RELU) v = fmaxf(v, 0.f);
                    C[base + nf * 16] = (__bf16)v;
                }
            }
    } else {
        float* C = (float*)Cp + e * sC;
        #pragma unroll
        for (int mf = 0; mf < 8; ++mf)
            #pragma unroll
            for (int j = 0; j < 4; ++j) {
                const size_t base = (size_t)(orow + mf * 16 + j) * N + ocol;
                #pragma unroll
                for (int nf = 0; nf < 4; ++nf) {
                    float v = acc[mf][nf][j];
                    if (RELU) v = fmaxf(v, 0.f);
                    C[base + nf * 16] = v;
                }
            }
    }
}

// ---------------- fallback 128x128 kernel (tiers B-E) ----------------
template<int AMODE, int BMODE, bool RELU, bool OUT_BF16>
__global__ __launch_bounds__(256)
void gemm2(const void* __restrict__ Ap, const void* __restrict__ Bp,
           void* __restrict__ Cp, int N, int K, int tiles_m, int tiles_n,
           size_t sA, size_t sB, size_t sC)
{
    constexpr int LA = (AMODE == 0) ? BK : LSTR;
    constexpr int LB = (BMODE == 0) ? BK : LSTR;
    __shared__ __bf16 As[BM * LA];
    __shared__ __bf16 Bs[BN * LB];

    int bid = blockIdx.x;
    const int chunk = gridDim.x >> 3;
    bid = (bid & 7) * chunk + (bid >> 3);

    const int per_e = tiles_m * tiles_n;
    const int e  = bid / per_e;
    const int t  = bid - e * per_e;
    const int tn = t / tiles_m;
    const int tm = t - tn * tiles_m;

    const int tid = threadIdx.x;
    const int l   = tid & 63;
    const int wid = tid >> 6;
    const int wr  = wid >> 1, wc = wid & 1;
    const int lr  = l & 15;
    const int kg  = l >> 4;
    const int srow = tid >> 1;
    const int scol = (tid & 1) << 4;

    const __bf16* gA = nullptr; __bf16* lA = nullptr;
    const float*  pAf = nullptr; __bf16* aWr = nullptr;
    float4 A0, A1, A2, A3;
    if constexpr (AMODE == 0) {
        gA = (const __bf16*)Ap + e * sA
           + (size_t)(tm * BM + wid * 16 + (l >> 2)) * K + (l & 3) * 8;
        lA = As + wid * 512;
    } else {
        pAf = (const float*)Ap + e * sA + (size_t)(tm * BM + srow) * K + scol;
        aWr = As + srow * LA + scol;
        A0 = *(const float4*)(pAf);      A1 = *(const float4*)(pAf + 4);
        A2 = *(const float4*)(pAf + 8);  A3 = *(const float4*)(pAf + 12);
    }
    const __bf16* gB = nullptr; __bf16* lB = nullptr;
    const float*  pBf = nullptr; __bf16* bWr = nullptr;
    float4 B0, B1, B2, B3;
    if constexpr (BMODE == 0) {
        gB = (const __bf16*)Bp + e * sB
           + (size_t)(tn * BN + wid * 16 + (l >> 2)) * K + (l & 3) * 8;
        lB = Bs + wid * 512;
    } else {
        pBf = (const float*)Bp + e * sB + (size_t)(tn * BN + srow) * K + scol;
        bWr = Bs + srow * LB + scol;
        B0 = *(const float4*)(pBf);      B1 = *(const float4*)(pBf + 4);
        B2 = *(const float4*)(pBf + 8);  B3 = *(const float4*)(pBf + 12);
    }

    const __bf16* aRd = As + (wr * 64 + lr) * LA + kg * 8;
    const __bf16* bRd = Bs + (wc * 64 + lr) * LB + kg * 8;

    f32x4 acc[4][4];
    #pragma unroll
    for (int m = 0; m < 4; ++m)
        #pragma unroll
        for (int n = 0; n < 4; ++n)
            acc[m][n] = (f32x4){0.f, 0.f, 0.f, 0.f};

    const int NT = K / BK;
    for (int kt = 0; kt < NT; ++kt) {
        if (kt) __syncthreads();
        if constexpr (AMODE == 0) {
            gload16(gA, lA);
            gload16(gA + (size_t)64 * K, lA + 2048);
            gA += BK;
        } else {
            *(bf16x8*)(aWr)     = cvt8(A0, A1);
            *(bf16x8*)(aWr + 8) = cvt8(A2, A3);
        }
        if constexpr (BMODE == 0) {
            gload16(gB, lB);
            gload16(gB + (size_t)64 * K, lB + 2048);
            gB += BK;
        } else {
            *(bf16x8*)(bWr)     = cvt8(B0, B1);
            *(bf16x8*)(bWr + 8) = cvt8(B2, B3);
        }
        __syncthreads();

        if (kt + 1 < NT) {
            if constexpr (AMODE == 2) {
                pAf += BK;
                A0 = *(const float4*)(pAf);      A1 = *(const float4*)(pAf + 4);
                A2 = *(const float4*)(pAf + 8);  A3 = *(const float4*)(pAf + 12);
            }
            if constexpr (BMODE == 2) {
                pBf += BK;
                B0 = *(const float4*)(pBf);      B1 = *(const float4*)(pBf + 4);
                B2 = *(const float4*)(pBf + 8);  B3 = *(const float4*)(pBf + 12);
            }
        }

        bf16x8 af[4], bfr[4];
        #pragma unroll
        for (int m = 0; m < 4; ++m) af[m]  = *(const bf16x8*)(aRd + m * 16 * LA);
        #pragma unroll
        for (int n = 0; n < 4; ++n) bfr[n] = *(const bf16x8*)(bRd + n * 16 * LB);
        #pragma unroll
        for (int m = 0; m < 4; ++m)
            #pragma unroll
            for (int n = 0; n < 4; ++n)
                acc[m][n] = __builtin_amdgcn_mfma_f32_16x16x32_bf16(af[m], bfr[n], acc[m][n], 0, 0, 0);
    }

    const int orow = tm * BM + wr * 64 + kg * 4;
    const int ocol = tn * BN + wc * 64 + lr;
    if constexpr (OUT_BF16) {
        __bf16* C = (__bf16*)Cp + e * sC;
        #pragma unroll
        for (int m = 0; m < 4; ++m)
            #pragma unroll
            for (int j = 0; j < 4; ++j) {
                const size_t base = (size_t)(orow + m * 16 + j) * N + ocol;
                #pragma unroll
                for (int n = 0; n < 4; ++n) {
                    float v = acc[m][n][j];
                    if (RELU) v = fmaxf(v, 0.f);
                    C[base + n * 16] = (__bf16)v;
                }
            }
    } else {
        float* C = (float*)Cp + e * sC;
        #pragma unroll
        for (int m = 0; m < 4; ++m)
            #pragma unroll
            for (int j = 0; j < 4; ++j) {
                const size_t base = (size_t)(orow + m * 16 + j) * N + ocol;
                #pragma unroll
                for (int n = 0; n < 4; ++n) {
                    float v = acc[m][n][j];
                    if (RELU) v = fmaxf(v, 0.f);
                    C[base + n * 16] = v;
                }
            }
    }
}

extern "C" void kernel_launch(void* const* d_in, const int* in_sizes, int n_in,
                              void* d_out, int out_size, void* d_ws, size_t ws_size,
                              hipStream_t stream) {
    const float* x  = (const float*)d_in[0];   // [8, 2048, 1024]
    const float* w1 = (const float*)d_in[1];   // [8, 4096, 1024]
    const float* w2 = (const float*)d_in[2];   // [8, 1024, 4096]
    float* out = (float*)d_out;                // [8, 2048, 1024]

    const size_t SZ_F  = (size_t)EXPERTS * TOK * DH * sizeof(__bf16);  // 134.2 MB
    const size_t SZ_X  = (size_t)EXPERTS * TOK * DM * sizeof(__bf16);
    const size_t SZ_W1 = (size_t)EXPERTS * DH * DM * sizeof(__bf16);
    const size_t SZ_W2 = (size_t)EXPERTS * DM * DH * sizeof(__bf16);

    char* wsb = (char*)d_ws;
    __bf16* ffn1 = (__bf16*)wsb;

    const dim3 blk(256);
    const dim3 cgrid(2048);
    const int NX  = EXPERTS * TOK * DM / 8;
    const int NW1 = EXPERTS * DH * DM / 8;
    const int NW2 = EXPERTS * DM * DH / 8;

    const size_t eA1 = (size_t)TOK * DM, eB1 = (size_t)DH * DM, eC1 = (size_t)TOK * DH;
    const size_t eA2 = (size_t)TOK * DH, eB2 = (size_t)DM * DH, eC2 = (size_t)TOK * DM;

    if (ws_size >= SZ_F + SZ_X + SZ_W1 + SZ_W2) {
        // Tier A: fused cvt, then both GEMMs on the 1-barrier/phase kernel
        __bf16* xb  = (__bf16*)(wsb + SZ_F);
        __bf16* w1b = (__bf16*)(wsb + SZ_F + SZ_X);
        __bf16* w2b = (__bf16*)(wsb + SZ_F + SZ_X + SZ_W1);
        hipLaunchKernelGGL(cvt_all, cgrid, blk, 0, stream,
            x, w1, w2, xb, w1b, w2b, NX, NW1, NX + NW1 + NW2);
        const dim3 g1(EXPERTS * (TOK / 256) * (DH / 256));   // 1024
        const dim3 g2(EXPERTS * (TOK / 256) * (DM / 256));   // 256
        hipLaunchKernelGGL((gemm8<true, true>), g1, dim3(512), 0, stream,
            xb, w1b, ffn1, DH, DM, TOK / 256, DH / 256, eA1, eB1, eC1);
        hipLaunchKernelGGL((gemm8<false, false>), g2, dim3(512), 0, stream,
            ffn1, w2b, out, DM, DH, TOK / 256, DM / 256, eA2, eB2, eC2);
    } else if (ws_size >= SZ_F + SZ_X + SZ_W1) {
        __bf16* xb  = (__bf16*)(wsb + SZ_F);
        __bf16* w1b = (__bf16*)(wsb + SZ_F + SZ_X);
        hipLaunchKernelGGL(cvt_all, cgrid, blk, 0, stream,
            x, w1, w1, xb, w1b, w1b, NX, NW1, NX + NW1);
        const dim3 g1(EXPERTS * (TOK / 256) * (DH / 256));
        const dim3 g2(EXPERTS * (TOK / BM) * (DM / BN));
        hipLaunchKernelGGL((gemm8<true, true>), g1, dim3(512), 0, stream,
            xb, w1b, ffn1, DH, DM, TOK / 256, DH / 256, eA1, eB1, eC1);
        hipLaunchKernelGGL((gemm2<0, 2, false, false>), g2, blk, 0, stream,
            ffn1, w2, out, DM, DH, TOK / BM, DM / BN, eA2, eB2, eC2);
    } else if (ws_size >= SZ_F + SZ_W1) {
        __bf16* w1b = (__bf16*)(wsb + SZ_F);
        hipLaunchKernelGGL(cvt_all, cgrid, blk, 0, stream,
            w1, w1, w1, w1b, w1b, w1b, NW1, 0, NW1);
        const dim3 g1(EXPERTS * (TOK / BM) * (DH / BN));
        const dim3 g2(EXPERTS * (TOK / BM) * (DM / BN));
        hipLaunchKernelGGL((gemm2<2, 0, true, true>), g1, blk, 0, stream,
            x, w1b, ffn1, DH, DM, TOK / BM, DH / BN, eA1, eB1, eC1);
        hipLaunchKernelGGL((gemm2<0, 2, false, false>), g2, blk, 0, stream,
            ffn1, w2, out, DM, DH, TOK / BM, DM / BN, eA2, eB2, eC2);
    } else if (ws_size >= SZ_F) {
        const dim3 g1(EXPERTS * (TOK / BM) * (DH / BN));
        const dim3 g2(EXPERTS * (TOK / BM) * (DM / BN));
        hipLaunchKernelGGL((gemm2<2, 2, true, true>), g1, blk, 0, stream,
            x, w1, ffn1, DH, DM, TOK / BM, DH / BN, eA1, eB1, eC1);
        hipLaunchKernelGGL((gemm2<0, 2, false, false>), g2, blk, 0, stream,
            ffn1, w2, out, DM, DH, TOK / BM, DM / BN, eA2, eB2, eC2);
    } else {
        int rows = (int)((ws_size / ((size_t)DH * sizeof(__bf16))) / BM) * BM;
        if (rows <= 0) rows = BM;
        if (rows > TOK) rows = TOK;
        for (int e = 0; e < EXPERTS; ++e) {
            for (int r0 = 0; r0 < TOK; r0 += rows) {
                int mr = (TOK - r0 < rows) ? (TOK - r0) : rows;
                dim3 cg1((mr / BM) * (DH / BN));
                hipLaunchKernelGGL((gemm2<2, 2, true, true>), cg1, blk, 0, stream,
                    x + ((size_t)e * TOK + r0) * DM, w1 + (size_t)e * DH * DM, ffn1,
                    DH, DM, mr / BM, DH / BN, (size_t)0, (size_t)0, (size_t)0);
                dim3 cg2((mr / BM) * (DM / BN));
                hipLaunchKernelGGL((gemm2<0, 2, false, false>), cg2, blk, 0, stream,
                    ffn1, w2 + (size_t)e * DM * DH, out + ((size_t)e * TOK + r0) * DM,
                    DM, DH, mr / BM, DM / BN, (size_t)0, (size_t)0, (size_t)0);
            }
        }
    }
}